// Round 16
// baseline (867.866 us; speedup 1.0000x reference)
//
#include <hip/hip_runtime.h>

#define TT 2000
#define NB 100
#define N1 100
#define KIN 784
#define CT1 1998
#define NC1 10000
#define CT2 1999
#define NC2 1000
#define NPAD 112
#define KPAD 800
#define S1 256
#define NCHUNK 8

typedef __attribute__((ext_vector_type(8))) short bf16x8;
typedef __attribute__((ext_vector_type(4))) float f32x4;

__device__ __forceinline__ float rcp_f(float d) { return __builtin_amdgcn_rcpf(d); }
__device__ __forceinline__ float sigmoid3(float V) {
  return rcp_f(1.0f + __expf((20.0f - V) * (1.0f / 3.0f)));
}
// sigmoid((V-20)/3) from u = exp((25-V)/9): exp((20-V)/3) = u^3 * e^{-5/3}
__device__ __forceinline__ float sig_from_u(float u) {
  float u3 = u * u * u;
  return rcp_f(1.0f + 0.18887560f * u3);
}
__device__ __forceinline__ float gate_u(float a, float b, float p) {
  float s = 0.005f * (a + b);
  return (a * 0.01f + (1.0f - s) * p) * rcp_f(s + 1.0f);
}
// HH CN step; n/m gates rescaled (one rcp each, singularity patches exact);
// y-gate coefficients (ay,by,ry) precomputed off-chain; returns u_n.
__device__ __forceinline__ float hh_step(float& V, float& m, float& n, float& h,
                                         float& y, float ay, float by, float ry) {
  float p1 = 40.0f * m * m * m * h;
  float nn2 = n * n;
  float p2 = 35.0f * nn2 * nn2;
  float Gs = 0.005f * (p1 + p2 + 0.3f + 0.04f * y);
  float E = p1 * 55.0f + p2 * (-77.0f) + (0.3f * (-65.0f));
  float Vn = (V * (1.0f - Gs) + 0.01f * (E + 1.5f)) * rcp_f(1.0f + Gs);

  float u_n = __expf((25.0f - Vn) * (1.0f / 9.0f));
  float u_m = __expf((-Vn - 35.0f) * (1.0f / 9.0f));
  float aH  = 0.25f * __expf((-Vn - 90.0f) * (1.0f / 12.0f));
  float bH  = 0.25f * __expf((Vn + 34.0f) * (1.0f / 12.0f));

  float dn = 1.0f - u_n, dm = 1.0f - u_m;
  float Bn = 0.02f * (Vn - 25.0f);
  float Am = 0.182f * (Vn + 35.0f);
  if (dn == 0.0f) { Bn = 0.18f;  dn = 1.0f; }
  if (dm == 0.0f) { Am = 1.638f; dm = 1.0f; }
  float Pn = 0.005f * Bn * (1.0f + 0.1f * u_n);
  float Pm = 0.005f * Am * (1.0f + 0.6813187f * u_m);
  n = (Bn * 0.01f + (dn - Pn) * n) * rcp_f(dn + Pn);
  m = (Am * 0.01f + (dm - Pm) * m) * rcp_f(dm + Pm);
  h = gate_u(aH, bH, h);
  y = (ay + by * y) * ry;
  V = Vn;
  return u_n;
}

__device__ __forceinline__ short bf16rne(float x) {
  unsigned u = __builtin_bit_cast(unsigned, x);
  unsigned r = u + 0x7fffu + ((u >> 16) & 1u);
  return (short)(r >> 16);
}
__device__ __forceinline__ float bf2f(short s) {
  unsigned u = ((unsigned)(unsigned short)s) << 16;
  return __builtin_bit_cast(float, u);
}
__device__ __forceinline__ void bsplit(float x, short& h, short& l) {
  h = bf16rne(x);
  l = bf16rne(x - bf2f(h));
}

__global__ __launch_bounds__(256) void prep_w1(const float* __restrict__ W1,
                                               short* __restrict__ W1h,
                                               short* __restrict__ W1l) {
  int idx = blockIdx.x * 256 + threadIdx.x;
  if (idx >= NPAD * KPAD) return;
  int nrow = idx / KPAD, k = idx - nrow * KPAD;
  float v = (nrow < N1 && k < KIN) ? W1[nrow * KIN + k] : 0.0f;
  short h, l; bsplit(v, h, l);
  W1h[idx] = h; W1l[idx] = l;
}

// ---------- gemm chunk body: software-pipelined K-loop, 128-row subtiles ----------
__device__ void gemm_body(const float* __restrict__ batch, const short* __restrict__ W1h,
                          const short* __restrict__ W1l, float* __restrict__ z1s,
                          int k, int b, char* smem) {
  short (*AsH)[32] = (short(*)[32])(smem);
  short (*AsL)[32] = (short(*)[32])(smem + 8192);
  short (*BsH)[32] = (short(*)[32])(smem + 16384);
  short (*BsL)[32] = (short(*)[32])(smem + 16384 + 7168);

  const int tid = threadIdx.x;
  const int cBeg = k * S1;
  const int cEnd = (cBeg + S1 < CT1) ? (cBeg + S1) : CT1;

  const int w = tid >> 6;
  const int lane = tid & 63;
  const int lr = lane & 15;
  const int kg = lane >> 4;
  const int srow = tid >> 1;
  const int kc = (tid & 1) * 16;
  const int brow = tid >> 1;
  const bool bAct = (tid < 224);
  const short* bhSrc = W1h + (size_t)brow * KPAD + kc;
  const short* blSrc = W1l + (size_t)brow * KPAD + kc;

  for (int tBeg = cBeg; tBeg < cEnd; tBeg += 128) {
    const int rows = ((cEnd - tBeg) < 128) ? (cEnd - tBeg) : 128;
    const size_t rBeg = (size_t)b * CT1 + tBeg;
    int tCl = tBeg + ((srow < rows) ? srow : (rows - 1));
    const float* aSrc = batch + ((size_t)b * TT + tCl) * KIN + kc;

    float4 a0, a1, a2, a3;
    int4 bh0, bh1, bl0, bl1;
    // prologue: load K-tile 0
    a0 = a1 = a2 = a3 = make_float4(0.f, 0.f, 0.f, 0.f);
    if (kc < KIN) {
      a0 = *(const float4*)(aSrc);
      a1 = *(const float4*)(aSrc + 4);
      a2 = *(const float4*)(aSrc + 8);
      a3 = *(const float4*)(aSrc + 12);
    }
    if (bAct) {
      bh0 = *(const int4*)(bhSrc);
      bh1 = *(const int4*)(bhSrc + 8);
      bl0 = *(const int4*)(blSrc);
      bl1 = *(const int4*)(blSrc + 8);
    }

    f32x4 acc[2][7];
#pragma unroll
    for (int mt = 0; mt < 2; ++mt)
#pragma unroll
      for (int nt = 0; nt < 7; ++nt) acc[mt][nt] = (f32x4){0.f, 0.f, 0.f, 0.f};

    for (int kt = 0; kt < KPAD; kt += 32) {
      __syncthreads();   // previous tile's compute done; LDS writable
      {
        float av[16] = {a0.x, a0.y, a0.z, a0.w, a1.x, a1.y, a1.z, a1.w,
                        a2.x, a2.y, a2.z, a2.w, a3.x, a3.y, a3.z, a3.w};
        bf16x8 h0, h1, l0, l1;
#pragma unroll
        for (int i = 0; i < 8; ++i) {
          short hh, ll;
          bsplit(av[i], hh, ll);     h0[i] = hh; l0[i] = ll;
          bsplit(av[8 + i], hh, ll); h1[i] = hh; l1[i] = ll;
        }
        *(bf16x8*)&AsH[srow][kc] = h0;
        *(bf16x8*)&AsH[srow][kc + 8] = h1;
        *(bf16x8*)&AsL[srow][kc] = l0;
        *(bf16x8*)&AsL[srow][kc + 8] = l1;
        if (bAct) {
          *(int4*)&BsH[brow][kc] = bh0;
          *(int4*)&BsH[brow][kc + 8] = bh1;
          *(int4*)&BsL[brow][kc] = bl0;
          *(int4*)&BsL[brow][kc + 8] = bl1;
        }
      }
      __syncthreads();   // LDS ready

      // preload next K-tile (latency hides under the MFMAs below)
      int kn = kt + 32;
      if (kn < KPAD) {
        a0 = a1 = a2 = a3 = make_float4(0.f, 0.f, 0.f, 0.f);
        if (kn + kc < KIN) {
          a0 = *(const float4*)(aSrc + kn);
          a1 = *(const float4*)(aSrc + kn + 4);
          a2 = *(const float4*)(aSrc + kn + 8);
          a3 = *(const float4*)(aSrc + kn + 12);
        }
        if (bAct) {
          bh0 = *(const int4*)(bhSrc + kn);
          bh1 = *(const int4*)(bhSrc + kn + 8);
          bl0 = *(const int4*)(blSrc + kn);
          bl1 = *(const int4*)(blSrc + kn + 8);
        }
      }

      bf16x8 aH0 = *(bf16x8*)&AsH[w * 32 + lr][kg * 8];
      bf16x8 aH1 = *(bf16x8*)&AsH[w * 32 + 16 + lr][kg * 8];
      bf16x8 aL0 = *(bf16x8*)&AsL[w * 32 + lr][kg * 8];
      bf16x8 aL1 = *(bf16x8*)&AsL[w * 32 + 16 + lr][kg * 8];
#pragma unroll
      for (int nt = 0; nt < 7; ++nt) {
        bf16x8 bH = *(bf16x8*)&BsH[nt * 16 + lr][kg * 8];
        bf16x8 bL = *(bf16x8*)&BsL[nt * 16 + lr][kg * 8];
        acc[0][nt] = __builtin_amdgcn_mfma_f32_16x16x32_bf16(aH0, bH, acc[0][nt], 0, 0, 0);
        acc[0][nt] = __builtin_amdgcn_mfma_f32_16x16x32_bf16(aH0, bL, acc[0][nt], 0, 0, 0);
        acc[0][nt] = __builtin_amdgcn_mfma_f32_16x16x32_bf16(aL0, bH, acc[0][nt], 0, 0, 0);
        acc[1][nt] = __builtin_amdgcn_mfma_f32_16x16x32_bf16(aH1, bH, acc[1][nt], 0, 0, 0);
        acc[1][nt] = __builtin_amdgcn_mfma_f32_16x16x32_bf16(aH1, bL, acc[1][nt], 0, 0, 0);
        acc[1][nt] = __builtin_amdgcn_mfma_f32_16x16x32_bf16(aL1, bH, acc[1][nt], 0, 0, 0);
      }
    }

#pragma unroll
    for (int nt = 0; nt < 7; ++nt) {
      int n = nt * 16 + lr;
      if (n < 100) {
#pragma unroll
        for (int mt = 0; mt < 2; ++mt) {
          int rloc = w * 32 + mt * 16 + kg * 4;
          f32x4 d = acc[mt][nt];
#pragma unroll
          for (int rr = 0; rr < 4; ++rr) {
            if (rloc + rr < rows) z1s[(rBeg + rloc + rr) * 100 + n] = d[rr];
          }
        }
      }
    }
    __syncthreads();
  }
}

// ---------- L1 scan chunk: stores RAW u_n (sigmoid applied by z2 stage) ----------
__device__ void l1_body(const float* __restrict__ z1s, float* __restrict__ T1s,
                        float* __restrict__ st, int k, int lb) {
  int c = lb * 256 + threadIdx.x;
  if (c >= NC1) return;
  int b = c / 100, ni = c - b * 100;
  int tBeg = k * S1;
  int tEnd = (tBeg + S1 < CT1) ? (tBeg + S1) : CT1;
  int nsteps = tEnd - tBeg;
  float* SV = st; float* SM = st + NC1; float* SN = st + 2 * NC1;
  float* SH = st + 3 * NC1; float* SY = st + 4 * NC1;
  float V, m, n, h, y;
  if (k == 0) {
    V = -70.f; m = 0.f; n = 0.f; h = 1.f; y = 0.f;
    T1s[c] = __expf((25.0f + 70.0f) * (1.0f / 9.0f));   // u for V0=-70
  } else { V = SV[c]; m = SM[c]; n = SN[c]; h = SH[c]; y = SY[c]; }
  const float* zp = z1s + ((size_t)b * CT1 + tBeg) * 100 + ni;
  float* tp = T1s + (size_t)(tBeg + 1) * NC1 + c;
  float zc[8], zx[8], ay[8], by[8], ry[8];
#pragma unroll
  for (int j = 0; j < 8; ++j) zc[j] = zp[j * 100];
  zp += 800;
  int NW = nsteps >> 3, tail = nsteps & 7;
  for (int i = 0; i < NW; ++i) {
#pragma unroll
    for (int j = 0; j < 8; ++j) zx[j] = zp[j * 100];   // z1s padded: unconditional
    zp += 800;
#pragma unroll
    for (int j = 0; j < 8; ++j) {                      // y-gate coefs off the chain
      float s = 0.005f * zc[j] + 0.0005f;
      ay[j] = zc[j] * 0.01f; by[j] = 1.0f - s; ry[j] = rcp_f(1.0f + s);
    }
#pragma unroll
    for (int j = 0; j < 8; ++j) {
      float u = hh_step(V, m, n, h, y, ay[j], by[j], ry[j]);
      *tp = u;                                         // raw u; sig in z2
      tp += NC1;
    }
#pragma unroll
    for (int j = 0; j < 8; ++j) zc[j] = zx[j];
  }
  for (int j = 0; j < tail; ++j) {
    float s = 0.005f * zc[j] + 0.0005f;
    float u = hh_step(V, m, n, h, y, zc[j] * 0.01f, 1.0f - s, rcp_f(1.0f + s));
    *tp = u;
    tp += NC1;
  }
  SV[c] = V; SM[c] = m; SN[c] = n; SH[c] = h; SY[c] = y;
}

// ---------- z2 chunk: applies sig_from_u to T1 (moved off the l1 chain) ----------
__device__ void z2_body(const float* __restrict__ T1s, const float* __restrict__ W2,
                        float* __restrict__ z2s, int k, int zb, char* smem) {
  float* w2 = (float*)smem;
  const int tid = threadIdx.x;
  if (tid < 250) *(float4*)&w2[tid * 4] = *(const float4*)&W2[tid * 4];
  __syncthreads();
  int tBeg = k * S1;
  int tEnd = (tBeg + S1 < CT2) ? (tBeg + S1) : CT2;
  int r = tBeg * NB + zb * 256 + tid;
  if (r >= tEnd * NB) return;
  const float* in = T1s + (size_t)r * 100;
  float acc[10];
#pragma unroll
  for (int o = 0; o < 10; ++o) acc[o] = 0.f;
  for (int k4 = 0; k4 < 25; ++k4) {
    float4 v = *(const float4*)(in + k4 * 4);
    v.x = sig_from_u(v.x); v.y = sig_from_u(v.y);
    v.z = sig_from_u(v.z); v.w = sig_from_u(v.w);
#pragma unroll
    for (int o = 0; o < 10; ++o) {
      float4 w = *(const float4*)&w2[o * 100 + k4 * 4];
      acc[o] += v.x * w.x + v.y * w.y + v.z * w.z + v.w * w.w;
    }
  }
  float* op = z2s + (size_t)r * 10;
#pragma unroll
  for (int o = 0; o < 10; o += 2) *(float2*)(op + o) = make_float2(acc[o], acc[o + 1]);
}

// ---------- L2 scan chunk (sigmoid inline; writes final out) ----------
__device__ void l2_body(const float* __restrict__ z2s, float* __restrict__ out,
                        float* __restrict__ st, int k, int lb) {
  int c2 = lb * 256 + threadIdx.x;
  if (c2 >= NC2) return;
  int b = c2 / 10, o = c2 - b * 10;
  int tBeg = k * S1;
  int tEnd = (tBeg + S1 < CT2) ? (tBeg + S1) : CT2;
  int nsteps = tEnd - tBeg;
  float* SV = st; float* SM = st + NC2; float* SN = st + 2 * NC2;
  float* SH = st + 3 * NC2; float* SY = st + 4 * NC2;
  float V, m, n, h, y;
  if (k == 0) {
    V = -70.f; m = 0.f; n = 0.f; h = 1.f; y = 1.f;
    out[(size_t)b * TT * 10 + o] = sigmoid3(-70.f);
  } else { V = SV[c2]; m = SM[c2]; n = SN[c2]; h = SH[c2]; y = SY[c2]; }
  const float* zp = z2s + (size_t)tBeg * NC2 + c2;
  float* op = out + ((size_t)b * TT + tBeg + 1) * 10 + o;
  float zc[8], zx[8], ay[8], by[8], ry[8];
#pragma unroll
  for (int j = 0; j < 8; ++j) zc[j] = zp[j * NC2];
  zp += 8 * NC2;
  int NW = nsteps >> 3, tail = nsteps & 7;
  for (int i = 0; i < NW; ++i) {
#pragma unroll
    for (int j = 0; j < 8; ++j) zx[j] = zp[j * NC2];   // z2s padded: unconditional
    zp += 8 * NC2;
#pragma unroll
    for (int j = 0; j < 8; ++j) {
      float s = 0.005f * zc[j] + 0.0005f;
      ay[j] = zc[j] * 0.01f; by[j] = 1.0f - s; ry[j] = rcp_f(1.0f + s);
    }
#pragma unroll
    for (int j = 0; j < 8; ++j) {
      float u = hh_step(V, m, n, h, y, ay[j], by[j], ry[j]);
      *op = sig_from_u(u);
      op += 10;
    }
#pragma unroll
    for (int j = 0; j < 8; ++j) zc[j] = zx[j];
  }
  for (int j = 0; j < tail; ++j) {
    float s = 0.005f * zc[j] + 0.0005f;
    float u = hh_step(V, m, n, h, y, zc[j] * 0.01f, 1.0f - s, rcp_f(1.0f + s));
    *op = sig_from_u(u);
    op += 10;
  }
  SV[c2] = V; SM[c2] = m; SN[c2] = n; SH[c2] = h; SY[c2] = y;
}

// ---------- fused pipeline dispatch (first-fit ordering: scans first) ----------
__global__ __launch_bounds__(256) void fused_pipe(
    const float* __restrict__ batch, const short* __restrict__ W1h,
    const short* __restrict__ W1l, const float* __restrict__ W2,
    float* __restrict__ z1s, float* __restrict__ T1s, float* __restrict__ z2s,
    float* __restrict__ out, float* __restrict__ stL1, float* __restrict__ stL2,
    int kG, int kL1, int kZ2, int kL2,
    int nL1, int nL2, int nZ2, int nG) {
  __shared__ __align__(16) char smem[30720];
  int bid = (int)blockIdx.x;
  if (bid < nL1) { l1_body(z1s, T1s, stL1, kL1, bid); return; }
  bid -= nL1;
  if (bid < nL2) { l2_body(z2s, out, stL2, kL2, bid); return; }
  bid -= nL2;
  if (bid < nZ2) { z2_body(T1s, W2, z2s, kZ2, bid, smem); return; }
  bid -= nZ2;
  if (bid < nG) { gemm_body(batch, W1h, W1l, z1s, kG, bid, smem); }
}

extern "C" void kernel_launch(void* const* d_in, const int* in_sizes, int n_in,
                              void* d_out, int out_size, void* d_ws, size_t ws_size,
                              hipStream_t stream) {
  (void)in_sizes; (void)n_in; (void)out_size; (void)ws_size;
  const float* batch = (const float*)d_in[0];
  const float* W1 = (const float*)d_in[1];
  const float* W2 = (const float*)d_in[2];
  float* out = (float*)d_out;

  float* z1s = (float*)d_ws;                                   // NB*CT1 x 100 (+16-row pad)
  float* T1s = z1s + (size_t)NB * CT1 * 100 + 1600;            // CT2 x NC1
  float* z2s = T1s + (size_t)CT2 * NC1;                        // CT2 x NC2 (+16-row pad)
  short* W1h = (short*)(z2s + (size_t)CT2 * NC2 + 16000);
  short* W1l = W1h + (size_t)NPAD * KPAD;
  float* stL1 = (float*)(W1l + (size_t)NPAD * KPAD);           // 5 x NC1
  float* stL2 = stL1 + 5 * NC1;                                // 5 x NC2

  prep_w1<<<dim3((NPAD * KPAD + 255) / 256), dim3(256), 0, stream>>>(W1, W1h, W1l);

  for (int d = 0; d <= NCHUNK + 2; ++d) {
    int kG = d, kL1 = d - 1, kZ2 = d - 2, kL2 = d - 3;
    int nG = (kG >= 0 && kG < NCHUNK) ? NB : 0;
    int nL1 = (kL1 >= 0 && kL1 < NCHUNK) ? (NC1 + 255) / 256 : 0;       // 40
    int nZ2 = 0;
    if (kZ2 >= 0 && kZ2 < NCHUNK) {
      int tBeg = kZ2 * S1;
      int tEnd = (tBeg + S1 < CT2) ? (tBeg + S1) : CT2;
      nZ2 = ((tEnd - tBeg) * NB + 255) / 256;                           // <= 100
    }
    int nL2 = (kL2 >= 0 && kL2 < NCHUNK) ? (NC2 + 255) / 256 : 0;       // 4
    int grid = nL1 + nL2 + nZ2 + nG;
    if (grid == 0) continue;
    fused_pipe<<<dim3((unsigned)grid), dim3(256), 0, stream>>>(
        batch, W1h, W1l, W2, z1s, T1s, z2s, out, stL1, stL2,
        kG, kL1, kZ2, kL2, nL1, nL2, nZ2, nG);
  }
}

// Round 17
// 783.516 us; speedup vs baseline: 1.1077x; 1.1077x over previous
//
#include <hip/hip_runtime.h>

#define TT 2000
#define NB 100
#define N1 100
#define KIN 784
#define CT1 1998
#define NC1 10000
#define CT2 1999
#define NC2 1000
#define NPAD 112
#define KPAD 800
#define S1 128
#define NCHUNK 16

typedef __attribute__((ext_vector_type(8))) short bf16x8;
typedef __attribute__((ext_vector_type(4))) float f32x4;

__device__ __forceinline__ float rcp_f(float d) { return __builtin_amdgcn_rcpf(d); }
__device__ __forceinline__ float sigmoid3(float V) {
  return rcp_f(1.0f + __expf((20.0f - V) * (1.0f / 3.0f)));
}
// sigmoid((V-20)/3) from u = exp((25-V)/9): exp((20-V)/3) = u^3 * e^{-5/3}
__device__ __forceinline__ float sig_from_u(float u) {
  float u3 = u * u * u;
  return rcp_f(1.0f + 0.18887560f * u3);
}
__device__ __forceinline__ float gate_u(float a, float b, float p) {
  float s = 0.005f * (a + b);
  return (a * 0.01f + (1.0f - s) * p) * rcp_f(s + 1.0f);
}
// HH CN step; n/m gates rescaled (one rcp each, singularity patches exact);
// y-gate coefficients (ay,by,ry) precomputed off-chain; returns u_n.
__device__ __forceinline__ float hh_step(float& V, float& m, float& n, float& h,
                                         float& y, float ay, float by, float ry) {
  float p1 = 40.0f * m * m * m * h;
  float nn2 = n * n;
  float p2 = 35.0f * nn2 * nn2;
  float Gs = 0.005f * (p1 + p2 + 0.3f + 0.04f * y);
  float E = p1 * 55.0f + p2 * (-77.0f) + (0.3f * (-65.0f));
  float Vn = (V * (1.0f - Gs) + 0.01f * (E + 1.5f)) * rcp_f(1.0f + Gs);

  float u_n = __expf((25.0f - Vn) * (1.0f / 9.0f));
  float u_m = __expf((-Vn - 35.0f) * (1.0f / 9.0f));
  float aH  = 0.25f * __expf((-Vn - 90.0f) * (1.0f / 12.0f));
  float bH  = 0.25f * __expf((Vn + 34.0f) * (1.0f / 12.0f));

  float dn = 1.0f - u_n, dm = 1.0f - u_m;
  float Bn = 0.02f * (Vn - 25.0f);
  float Am = 0.182f * (Vn + 35.0f);
  if (dn == 0.0f) { Bn = 0.18f;  dn = 1.0f; }
  if (dm == 0.0f) { Am = 1.638f; dm = 1.0f; }
  float Pn = 0.005f * Bn * (1.0f + 0.1f * u_n);
  float Pm = 0.005f * Am * (1.0f + 0.6813187f * u_m);
  n = (Bn * 0.01f + (dn - Pn) * n) * rcp_f(dn + Pn);
  m = (Am * 0.01f + (dm - Pm) * m) * rcp_f(dm + Pm);
  h = gate_u(aH, bH, h);
  y = (ay + by * y) * ry;
  V = Vn;
  return u_n;
}

__device__ __forceinline__ short bf16rne(float x) {
  unsigned u = __builtin_bit_cast(unsigned, x);
  unsigned r = u + 0x7fffu + ((u >> 16) & 1u);
  return (short)(r >> 16);
}
__device__ __forceinline__ float bf2f(short s) {
  unsigned u = ((unsigned)(unsigned short)s) << 16;
  return __builtin_bit_cast(float, u);
}
__device__ __forceinline__ void bsplit(float x, short& h, short& l) {
  h = bf16rne(x);
  l = bf16rne(x - bf2f(h));
}

__global__ __launch_bounds__(256) void prep_w1(const float* __restrict__ W1,
                                               short* __restrict__ W1h,
                                               short* __restrict__ W1l) {
  int idx = blockIdx.x * 256 + threadIdx.x;
  if (idx >= NPAD * KPAD) return;
  int nrow = idx / KPAD, k = idx - nrow * KPAD;
  float v = (nrow < N1 && k < KIN) ? W1[nrow * KIN + k] : 0.0f;
  short h, l; bsplit(v, h, l);
  W1h[idx] = h; W1l[idx] = l;
}

// ---------- gemm chunk body: software-pipelined K-loop (R15-proven) ----------
__device__ void gemm_body(const float* __restrict__ batch, const short* __restrict__ W1h,
                          const short* __restrict__ W1l, float* __restrict__ z1s,
                          int k, int b, char* smem) {
  short (*AsH)[32] = (short(*)[32])(smem);
  short (*AsL)[32] = (short(*)[32])(smem + 8192);
  short (*BsH)[32] = (short(*)[32])(smem + 16384);
  short (*BsL)[32] = (short(*)[32])(smem + 16384 + 7168);

  const int tid = threadIdx.x;
  const int tBeg = k * S1;
  const int tEnd = (tBeg + S1 < CT1) ? (tBeg + S1) : CT1;
  const int rows = tEnd - tBeg;
  const size_t rBeg = (size_t)b * CT1 + tBeg;

  const int w = tid >> 6;
  const int lane = tid & 63;
  const int lr = lane & 15;
  const int kg = lane >> 4;
  const int srow = tid >> 1;
  const int kc = (tid & 1) * 16;
  const int brow = tid >> 1;
  const bool bAct = (tid < 224);

  int tCl = tBeg + ((srow < rows) ? srow : (rows - 1));
  const float* aSrc = batch + ((size_t)b * TT + tCl) * KIN + kc;
  const short* bhSrc = W1h + (size_t)brow * KPAD + kc;
  const short* blSrc = W1l + (size_t)brow * KPAD + kc;

  float4 a0, a1, a2, a3;
  int4 bh0, bh1, bl0, bl1;

  // prologue: load K-tile 0
  a0 = a1 = a2 = a3 = make_float4(0.f, 0.f, 0.f, 0.f);
  if (kc < KIN) {
    a0 = *(const float4*)(aSrc);
    a1 = *(const float4*)(aSrc + 4);
    a2 = *(const float4*)(aSrc + 8);
    a3 = *(const float4*)(aSrc + 12);
  }
  if (bAct) {
    bh0 = *(const int4*)(bhSrc);
    bh1 = *(const int4*)(bhSrc + 8);
    bl0 = *(const int4*)(blSrc);
    bl1 = *(const int4*)(blSrc + 8);
  }

  f32x4 acc[2][7];
#pragma unroll
  for (int mt = 0; mt < 2; ++mt)
#pragma unroll
    for (int nt = 0; nt < 7; ++nt) acc[mt][nt] = (f32x4){0.f, 0.f, 0.f, 0.f};

  for (int kt = 0; kt < KPAD; kt += 32) {
    __syncthreads();   // previous tile's compute done; LDS writable
    {
      float av[16] = {a0.x, a0.y, a0.z, a0.w, a1.x, a1.y, a1.z, a1.w,
                      a2.x, a2.y, a2.z, a2.w, a3.x, a3.y, a3.z, a3.w};
      bf16x8 h0, h1, l0, l1;
#pragma unroll
      for (int i = 0; i < 8; ++i) {
        short hh, ll;
        bsplit(av[i], hh, ll);     h0[i] = hh; l0[i] = ll;
        bsplit(av[8 + i], hh, ll); h1[i] = hh; l1[i] = ll;
      }
      *(bf16x8*)&AsH[srow][kc] = h0;
      *(bf16x8*)&AsH[srow][kc + 8] = h1;
      *(bf16x8*)&AsL[srow][kc] = l0;
      *(bf16x8*)&AsL[srow][kc + 8] = l1;
      if (bAct) {
        *(int4*)&BsH[brow][kc] = bh0;
        *(int4*)&BsH[brow][kc + 8] = bh1;
        *(int4*)&BsL[brow][kc] = bl0;
        *(int4*)&BsL[brow][kc + 8] = bl1;
      }
    }
    __syncthreads();   // LDS ready

    // preload next K-tile (latency hides under the MFMAs below)
    int kn = kt + 32;
    if (kn < KPAD) {
      a0 = a1 = a2 = a3 = make_float4(0.f, 0.f, 0.f, 0.f);
      if (kn + kc < KIN) {
        a0 = *(const float4*)(aSrc + kn);
        a1 = *(const float4*)(aSrc + kn + 4);
        a2 = *(const float4*)(aSrc + kn + 8);
        a3 = *(const float4*)(aSrc + kn + 12);
      }
      if (bAct) {
        bh0 = *(const int4*)(bhSrc + kn);
        bh1 = *(const int4*)(bhSrc + kn + 8);
        bl0 = *(const int4*)(blSrc + kn);
        bl1 = *(const int4*)(blSrc + kn + 8);
      }
    }

    bf16x8 aH0 = *(bf16x8*)&AsH[w * 32 + lr][kg * 8];
    bf16x8 aH1 = *(bf16x8*)&AsH[w * 32 + 16 + lr][kg * 8];
    bf16x8 aL0 = *(bf16x8*)&AsL[w * 32 + lr][kg * 8];
    bf16x8 aL1 = *(bf16x8*)&AsL[w * 32 + 16 + lr][kg * 8];
#pragma unroll
    for (int nt = 0; nt < 7; ++nt) {
      bf16x8 bH = *(bf16x8*)&BsH[nt * 16 + lr][kg * 8];
      bf16x8 bL = *(bf16x8*)&BsL[nt * 16 + lr][kg * 8];
      acc[0][nt] = __builtin_amdgcn_mfma_f32_16x16x32_bf16(aH0, bH, acc[0][nt], 0, 0, 0);
      acc[0][nt] = __builtin_amdgcn_mfma_f32_16x16x32_bf16(aH0, bL, acc[0][nt], 0, 0, 0);
      acc[0][nt] = __builtin_amdgcn_mfma_f32_16x16x32_bf16(aL0, bH, acc[0][nt], 0, 0, 0);
      acc[1][nt] = __builtin_amdgcn_mfma_f32_16x16x32_bf16(aH1, bH, acc[1][nt], 0, 0, 0);
      acc[1][nt] = __builtin_amdgcn_mfma_f32_16x16x32_bf16(aH1, bL, acc[1][nt], 0, 0, 0);
      acc[1][nt] = __builtin_amdgcn_mfma_f32_16x16x32_bf16(aL1, bH, acc[1][nt], 0, 0, 0);
    }
  }

#pragma unroll
  for (int nt = 0; nt < 7; ++nt) {
    int n = nt * 16 + lr;
    if (n < 100) {
#pragma unroll
      for (int mt = 0; mt < 2; ++mt) {
        int rloc = w * 32 + mt * 16 + kg * 4;
        f32x4 d = acc[mt][nt];
#pragma unroll
        for (int rr = 0; rr < 4; ++rr) {
          if (rloc + rr < rows) z1s[(rBeg + rloc + rr) * 100 + n] = d[rr];
        }
      }
    }
  }
}

// ---------- L1 scan chunk: stores RAW u_n (sigmoid applied by z2 stage) ----------
__device__ void l1_body(const float* __restrict__ z1s, float* __restrict__ T1s,
                        float* __restrict__ st, int k, int lb) {
  int c = lb * 256 + threadIdx.x;
  if (c >= NC1) return;
  int b = c / 100, ni = c - b * 100;
  int tBeg = k * S1;
  int tEnd = (tBeg + S1 < CT1) ? (tBeg + S1) : CT1;
  int nsteps = tEnd - tBeg;
  float* SV = st; float* SM = st + NC1; float* SN = st + 2 * NC1;
  float* SH = st + 3 * NC1; float* SY = st + 4 * NC1;
  float V, m, n, h, y;
  if (k == 0) {
    V = -70.f; m = 0.f; n = 0.f; h = 1.f; y = 0.f;
    T1s[c] = __expf((25.0f + 70.0f) * (1.0f / 9.0f));   // u for V0=-70
  } else { V = SV[c]; m = SM[c]; n = SN[c]; h = SH[c]; y = SY[c]; }
  const float* zp = z1s + ((size_t)b * CT1 + tBeg) * 100 + ni;
  float* tp = T1s + (size_t)(tBeg + 1) * NC1 + c;
  float zc[8], zx[8], ay[8], by[8], ry[8];
#pragma unroll
  for (int j = 0; j < 8; ++j) zc[j] = zp[j * 100];
  zp += 800;
  int NW = nsteps >> 3, tail = nsteps & 7;
  for (int i = 0; i < NW; ++i) {
#pragma unroll
    for (int j = 0; j < 8; ++j) zx[j] = zp[j * 100];   // z1s padded: unconditional
    zp += 800;
#pragma unroll
    for (int j = 0; j < 8; ++j) {                      // y-gate coefs off the chain
      float s = 0.005f * zc[j] + 0.0005f;
      ay[j] = zc[j] * 0.01f; by[j] = 1.0f - s; ry[j] = rcp_f(1.0f + s);
    }
#pragma unroll
    for (int j = 0; j < 8; ++j) {
      float u = hh_step(V, m, n, h, y, ay[j], by[j], ry[j]);
      *tp = u;                                         // raw u; sig in z2
      tp += NC1;
    }
#pragma unroll
    for (int j = 0; j < 8; ++j) zc[j] = zx[j];
  }
  for (int j = 0; j < tail; ++j) {
    float s = 0.005f * zc[j] + 0.0005f;
    float u = hh_step(V, m, n, h, y, zc[j] * 0.01f, 1.0f - s, rcp_f(1.0f + s));
    *tp = u;
    tp += NC1;
  }
  SV[c] = V; SM[c] = m; SN[c] = n; SH[c] = h; SY[c] = y;
}

// ---------- z2 chunk: applies sig_from_u to T1 (moved off the l1 chain) ----------
__device__ void z2_body(const float* __restrict__ T1s, const float* __restrict__ W2,
                        float* __restrict__ z2s, int k, int zb, char* smem) {
  float* w2 = (float*)smem;
  const int tid = threadIdx.x;
  if (tid < 250) *(float4*)&w2[tid * 4] = *(const float4*)&W2[tid * 4];
  __syncthreads();
  int tBeg = k * S1;
  int tEnd = (tBeg + S1 < CT2) ? (tBeg + S1) : CT2;
  int r = tBeg * NB + zb * 256 + tid;
  if (r >= tEnd * NB) return;
  const float* in = T1s + (size_t)r * 100;
  float acc[10];
#pragma unroll
  for (int o = 0; o < 10; ++o) acc[o] = 0.f;
  for (int k4 = 0; k4 < 25; ++k4) {
    float4 v = *(const float4*)(in + k4 * 4);
    v.x = sig_from_u(v.x); v.y = sig_from_u(v.y);
    v.z = sig_from_u(v.z); v.w = sig_from_u(v.w);
#pragma unroll
    for (int o = 0; o < 10; ++o) {
      float4 w = *(const float4*)&w2[o * 100 + k4 * 4];
      acc[o] += v.x * w.x + v.y * w.y + v.z * w.z + v.w * w.w;
    }
  }
  float* op = z2s + (size_t)r * 10;
#pragma unroll
  for (int o = 0; o < 10; o += 2) *(float2*)(op + o) = make_float2(acc[o], acc[o + 1]);
}

// ---------- L2 scan chunk (sigmoid inline; writes final out) ----------
__device__ void l2_body(const float* __restrict__ z2s, float* __restrict__ out,
                        float* __restrict__ st, int k, int lb) {
  int c2 = lb * 256 + threadIdx.x;
  if (c2 >= NC2) return;
  int b = c2 / 10, o = c2 - b * 10;
  int tBeg = k * S1;
  int tEnd = (tBeg + S1 < CT2) ? (tBeg + S1) : CT2;
  int nsteps = tEnd - tBeg;
  float* SV = st; float* SM = st + NC2; float* SN = st + 2 * NC2;
  float* SH = st + 3 * NC2; float* SY = st + 4 * NC2;
  float V, m, n, h, y;
  if (k == 0) {
    V = -70.f; m = 0.f; n = 0.f; h = 1.f; y = 1.f;
    out[(size_t)b * TT * 10 + o] = sigmoid3(-70.f);
  } else { V = SV[c2]; m = SM[c2]; n = SN[c2]; h = SH[c2]; y = SY[c2]; }
  const float* zp = z2s + (size_t)tBeg * NC2 + c2;
  float* op = out + ((size_t)b * TT + tBeg + 1) * 10 + o;
  float zc[8], zx[8], ay[8], by[8], ry[8];
#pragma unroll
  for (int j = 0; j < 8; ++j) zc[j] = zp[j * NC2];
  zp += 8 * NC2;
  int NW = nsteps >> 3, tail = nsteps & 7;
  for (int i = 0; i < NW; ++i) {
#pragma unroll
    for (int j = 0; j < 8; ++j) zx[j] = zp[j * NC2];   // z2s padded: unconditional
    zp += 8 * NC2;
#pragma unroll
    for (int j = 0; j < 8; ++j) {
      float s = 0.005f * zc[j] + 0.0005f;
      ay[j] = zc[j] * 0.01f; by[j] = 1.0f - s; ry[j] = rcp_f(1.0f + s);
    }
#pragma unroll
    for (int j = 0; j < 8; ++j) {
      float u = hh_step(V, m, n, h, y, ay[j], by[j], ry[j]);
      *op = sig_from_u(u);
      op += 10;
    }
#pragma unroll
    for (int j = 0; j < 8; ++j) zc[j] = zx[j];
  }
  for (int j = 0; j < tail; ++j) {
    float s = 0.005f * zc[j] + 0.0005f;
    float u = hh_step(V, m, n, h, y, zc[j] * 0.01f, 1.0f - s, rcp_f(1.0f + s));
    *op = sig_from_u(u);
    op += 10;
  }
  SV[c2] = V; SM[c2] = m; SN[c2] = n; SH[c2] = h; SY[c2] = y;
}

// ---------- fused pipeline dispatch (first-fit ordering: scans first) ----------
__global__ __launch_bounds__(256) void fused_pipe(
    const float* __restrict__ batch, const short* __restrict__ W1h,
    const short* __restrict__ W1l, const float* __restrict__ W2,
    float* __restrict__ z1s, float* __restrict__ T1s, float* __restrict__ z2s,
    float* __restrict__ out, float* __restrict__ stL1, float* __restrict__ stL2,
    int kG, int kL1, int kZ2, int kL2,
    int nL1, int nL2, int nZ2, int nG) {
  __shared__ __align__(16) char smem[30720];
  int bid = (int)blockIdx.x;
  if (bid < nL1) { l1_body(z1s, T1s, stL1, kL1, bid); return; }
  bid -= nL1;
  if (bid < nL2) { l2_body(z2s, out, stL2, kL2, bid); return; }
  bid -= nL2;
  if (bid < nZ2) { z2_body(T1s, W2, z2s, kZ2, bid, smem); return; }
  bid -= nZ2;
  if (bid < nG) { gemm_body(batch, W1h, W1l, z1s, kG, bid, smem); }
}

extern "C" void kernel_launch(void* const* d_in, const int* in_sizes, int n_in,
                              void* d_out, int out_size, void* d_ws, size_t ws_size,
                              hipStream_t stream) {
  (void)in_sizes; (void)n_in; (void)out_size; (void)ws_size;
  const float* batch = (const float*)d_in[0];
  const float* W1 = (const float*)d_in[1];
  const float* W2 = (const float*)d_in[2];
  float* out = (float*)d_out;

  float* z1s = (float*)d_ws;                                   // NB*CT1 x 100 (+16-row pad)
  float* T1s = z1s + (size_t)NB * CT1 * 100 + 1600;            // CT2 x NC1
  float* z2s = T1s + (size_t)CT2 * NC1;                        // CT2 x NC2 (+16-row pad)
  short* W1h = (short*)(z2s + (size_t)CT2 * NC2 + 16000);
  short* W1l = W1h + (size_t)NPAD * KPAD;
  float* stL1 = (float*)(W1l + (size_t)NPAD * KPAD);           // 5 x NC1
  float* stL2 = stL1 + 5 * NC1;                                // 5 x NC2

  prep_w1<<<dim3((NPAD * KPAD + 255) / 256), dim3(256), 0, stream>>>(W1, W1h, W1l);

  for (int d = 0; d <= NCHUNK + 2; ++d) {
    int kG = d, kL1 = d - 1, kZ2 = d - 2, kL2 = d - 3;
    int nG = (kG >= 0 && kG < NCHUNK) ? NB : 0;
    int nL1 = (kL1 >= 0 && kL1 < NCHUNK) ? (NC1 + 255) / 256 : 0;       // 40
    int nZ2 = 0;
    if (kZ2 >= 0 && kZ2 < NCHUNK) {
      int tBeg = kZ2 * S1;
      int tEnd = (tBeg + S1 < CT2) ? (tBeg + S1) : CT2;
      nZ2 = ((tEnd - tBeg) * NB + 255) / 256;                           // <= 50
    }
    int nL2 = (kL2 >= 0 && kL2 < NCHUNK) ? (NC2 + 255) / 256 : 0;       // 4
    int grid = nL1 + nL2 + nZ2 + nG;
    if (grid == 0) continue;
    fused_pipe<<<dim3((unsigned)grid), dim3(256), 0, stream>>>(
        batch, W1h, W1l, W2, z1s, T1s, z2s, out, stL1, stL2,
        kG, kL1, kZ2, kL2, nL1, nL2, nZ2, nG);
  }
}

// Round 18
// 688.091 us; speedup vs baseline: 1.2613x; 1.1387x over previous
//
#include <hip/hip_runtime.h>

#define TT 2000
#define NB 100
#define N1 100
#define KIN 784
#define CT1 1998
#define NC1 10000
#define CT2 1999
#define NC2 1000
#define NPAD 112
#define KPAD 800
#define S1 128
#define NCHUNK 16

typedef __attribute__((ext_vector_type(8))) short bf16x8;
typedef __attribute__((ext_vector_type(4))) float f32x4;

__device__ __forceinline__ float rcp_f(float d) { return __builtin_amdgcn_rcpf(d); }
__device__ __forceinline__ float sigmoid3(float V) {
  return rcp_f(1.0f + __expf((20.0f - V) * (1.0f / 3.0f)));
}
// sigmoid((V-20)/3) from u = exp((25-V)/9): exp((20-V)/3) = u^3 * e^{-5/3}
__device__ __forceinline__ float sig_from_u(float u) {
  float u3 = u * u * u;
  return rcp_f(1.0f + 0.18887560f * u3);
}
__device__ __forceinline__ float gate_u(float a, float b, float p) {
  float s = 0.005f * (a + b);
  return (a * 0.01f + (1.0f - s) * p) * rcp_f(s + 1.0f);
}
// HH CN step; n/m gates rescaled (one rcp each, singularity patches exact);
// y-gate coefficients (ay,by,ry) precomputed off-chain; returns u_n.
__device__ __forceinline__ float hh_step(float& V, float& m, float& n, float& h,
                                         float& y, float ay, float by, float ry) {
  float p1 = 40.0f * m * m * m * h;
  float nn2 = n * n;
  float p2 = 35.0f * nn2 * nn2;
  float Gs = 0.005f * (p1 + p2 + 0.3f + 0.04f * y);
  float E = p1 * 55.0f + p2 * (-77.0f) + (0.3f * (-65.0f));
  float Vn = (V * (1.0f - Gs) + 0.01f * (E + 1.5f)) * rcp_f(1.0f + Gs);

  float u_n = __expf((25.0f - Vn) * (1.0f / 9.0f));
  float u_m = __expf((-Vn - 35.0f) * (1.0f / 9.0f));
  float aH  = 0.25f * __expf((-Vn - 90.0f) * (1.0f / 12.0f));
  float bH  = 0.25f * __expf((Vn + 34.0f) * (1.0f / 12.0f));

  float dn = 1.0f - u_n, dm = 1.0f - u_m;
  float Bn = 0.02f * (Vn - 25.0f);
  float Am = 0.182f * (Vn + 35.0f);
  if (dn == 0.0f) { Bn = 0.18f;  dn = 1.0f; }
  if (dm == 0.0f) { Am = 1.638f; dm = 1.0f; }
  float Pn = 0.005f * Bn * (1.0f + 0.1f * u_n);
  float Pm = 0.005f * Am * (1.0f + 0.6813187f * u_m);
  n = (Bn * 0.01f + (dn - Pn) * n) * rcp_f(dn + Pn);
  m = (Am * 0.01f + (dm - Pm) * m) * rcp_f(dm + Pm);
  h = gate_u(aH, bH, h);
  y = (ay + by * y) * ry;
  V = Vn;
  return u_n;
}

__device__ __forceinline__ short bf16rne(float x) {
  unsigned u = __builtin_bit_cast(unsigned, x);
  unsigned r = u + 0x7fffu + ((u >> 16) & 1u);
  return (short)(r >> 16);
}
__device__ __forceinline__ float bf2f(short s) {
  unsigned u = ((unsigned)(unsigned short)s) << 16;
  return __builtin_bit_cast(float, u);
}
__device__ __forceinline__ void bsplit(float x, short& h, short& l) {
  h = bf16rne(x);
  l = bf16rne(x - bf2f(h));
}

__global__ __launch_bounds__(256) void prep_w1(const float* __restrict__ W1,
                                               short* __restrict__ W1h,
                                               short* __restrict__ W1l) {
  int idx = blockIdx.x * 256 + threadIdx.x;
  if (idx >= NPAD * KPAD) return;
  int nrow = idx / KPAD, k = idx - nrow * KPAD;
  float v = (nrow < N1 && k < KIN) ? W1[nrow * KIN + k] : 0.0f;
  short h, l; bsplit(v, h, l);
  W1h[idx] = h; W1l[idx] = l;
}

// ---------- whole GEMM as one dispatch: bid -> (b, chunk k) ----------
// Software-pipelined K-loop (R15-proven body). 1600 blocks, 4-5/CU -> full
// machine throughput; runs BEFORE the scan pipeline so scan rounds see no
// gemm HBM/MFMA contention.
__global__ __launch_bounds__(256) void gemm_all(const float* __restrict__ batch,
                                                const short* __restrict__ W1h,
                                                const short* __restrict__ W1l,
                                                float* __restrict__ z1s) {
  __shared__ __align__(16) char smem[30720];
  short (*AsH)[32] = (short(*)[32])(smem);
  short (*AsL)[32] = (short(*)[32])(smem + 8192);
  short (*BsH)[32] = (short(*)[32])(smem + 16384);
  short (*BsL)[32] = (short(*)[32])(smem + 16384 + 7168);

  const int tid = threadIdx.x;
  const int b = (int)blockIdx.x / NCHUNK;
  const int k = (int)blockIdx.x % NCHUNK;
  const int tBeg = k * S1;
  const int tEnd = (tBeg + S1 < CT1) ? (tBeg + S1) : CT1;
  const int rows = tEnd - tBeg;
  const size_t rBeg = (size_t)b * CT1 + tBeg;

  const int w = tid >> 6;
  const int lane = tid & 63;
  const int lr = lane & 15;
  const int kg = lane >> 4;
  const int srow = tid >> 1;
  const int kc = (tid & 1) * 16;
  const int brow = tid >> 1;
  const bool bAct = (tid < 224);

  int tCl = tBeg + ((srow < rows) ? srow : (rows - 1));
  const float* aSrc = batch + ((size_t)b * TT + tCl) * KIN + kc;
  const short* bhSrc = W1h + (size_t)brow * KPAD + kc;
  const short* blSrc = W1l + (size_t)brow * KPAD + kc;

  float4 a0, a1, a2, a3;
  int4 bh0, bh1, bl0, bl1;

  // prologue: load K-tile 0
  a0 = a1 = a2 = a3 = make_float4(0.f, 0.f, 0.f, 0.f);
  if (kc < KIN) {
    a0 = *(const float4*)(aSrc);
    a1 = *(const float4*)(aSrc + 4);
    a2 = *(const float4*)(aSrc + 8);
    a3 = *(const float4*)(aSrc + 12);
  }
  if (bAct) {
    bh0 = *(const int4*)(bhSrc);
    bh1 = *(const int4*)(bhSrc + 8);
    bl0 = *(const int4*)(blSrc);
    bl1 = *(const int4*)(blSrc + 8);
  }

  f32x4 acc[2][7];
#pragma unroll
  for (int mt = 0; mt < 2; ++mt)
#pragma unroll
    for (int nt = 0; nt < 7; ++nt) acc[mt][nt] = (f32x4){0.f, 0.f, 0.f, 0.f};

  for (int kt = 0; kt < KPAD; kt += 32) {
    __syncthreads();   // previous tile's compute done; LDS writable
    {
      float av[16] = {a0.x, a0.y, a0.z, a0.w, a1.x, a1.y, a1.z, a1.w,
                      a2.x, a2.y, a2.z, a2.w, a3.x, a3.y, a3.z, a3.w};
      bf16x8 h0, h1, l0, l1;
#pragma unroll
      for (int i = 0; i < 8; ++i) {
        short hh, ll;
        bsplit(av[i], hh, ll);     h0[i] = hh; l0[i] = ll;
        bsplit(av[8 + i], hh, ll); h1[i] = hh; l1[i] = ll;
      }
      *(bf16x8*)&AsH[srow][kc] = h0;
      *(bf16x8*)&AsH[srow][kc + 8] = h1;
      *(bf16x8*)&AsL[srow][kc] = l0;
      *(bf16x8*)&AsL[srow][kc + 8] = l1;
      if (bAct) {
        *(int4*)&BsH[brow][kc] = bh0;
        *(int4*)&BsH[brow][kc + 8] = bh1;
        *(int4*)&BsL[brow][kc] = bl0;
        *(int4*)&BsL[brow][kc + 8] = bl1;
      }
    }
    __syncthreads();   // LDS ready

    // preload next K-tile (latency hides under the MFMAs below)
    int kn = kt + 32;
    if (kn < KPAD) {
      a0 = a1 = a2 = a3 = make_float4(0.f, 0.f, 0.f, 0.f);
      if (kn + kc < KIN) {
        a0 = *(const float4*)(aSrc + kn);
        a1 = *(const float4*)(aSrc + kn + 4);
        a2 = *(const float4*)(aSrc + kn + 8);
        a3 = *(const float4*)(aSrc + kn + 12);
      }
      if (bAct) {
        bh0 = *(const int4*)(bhSrc + kn);
        bh1 = *(const int4*)(bhSrc + kn + 8);
        bl0 = *(const int4*)(blSrc + kn);
        bl1 = *(const int4*)(blSrc + kn + 8);
      }
    }

    bf16x8 aH0 = *(bf16x8*)&AsH[w * 32 + lr][kg * 8];
    bf16x8 aH1 = *(bf16x8*)&AsH[w * 32 + 16 + lr][kg * 8];
    bf16x8 aL0 = *(bf16x8*)&AsL[w * 32 + lr][kg * 8];
    bf16x8 aL1 = *(bf16x8*)&AsL[w * 32 + 16 + lr][kg * 8];
#pragma unroll
    for (int nt = 0; nt < 7; ++nt) {
      bf16x8 bH = *(bf16x8*)&BsH[nt * 16 + lr][kg * 8];
      bf16x8 bL = *(bf16x8*)&BsL[nt * 16 + lr][kg * 8];
      acc[0][nt] = __builtin_amdgcn_mfma_f32_16x16x32_bf16(aH0, bH, acc[0][nt], 0, 0, 0);
      acc[0][nt] = __builtin_amdgcn_mfma_f32_16x16x32_bf16(aH0, bL, acc[0][nt], 0, 0, 0);
      acc[0][nt] = __builtin_amdgcn_mfma_f32_16x16x32_bf16(aL0, bH, acc[0][nt], 0, 0, 0);
      acc[1][nt] = __builtin_amdgcn_mfma_f32_16x16x32_bf16(aH1, bH, acc[1][nt], 0, 0, 0);
      acc[1][nt] = __builtin_amdgcn_mfma_f32_16x16x32_bf16(aH1, bL, acc[1][nt], 0, 0, 0);
      acc[1][nt] = __builtin_amdgcn_mfma_f32_16x16x32_bf16(aL1, bH, acc[1][nt], 0, 0, 0);
    }
  }

#pragma unroll
  for (int nt = 0; nt < 7; ++nt) {
    int n = nt * 16 + lr;
    if (n < 100) {
#pragma unroll
      for (int mt = 0; mt < 2; ++mt) {
        int rloc = w * 32 + mt * 16 + kg * 4;
        f32x4 d = acc[mt][nt];
#pragma unroll
        for (int rr = 0; rr < 4; ++rr) {
          if (rloc + rr < rows) z1s[(rBeg + rloc + rr) * 100 + n] = d[rr];
        }
      }
    }
  }
}

// ---------- L1 scan chunk: stores RAW u_n (sigmoid applied by z2 stage) ----------
__device__ void l1_body(const float* __restrict__ z1s, float* __restrict__ T1s,
                        float* __restrict__ st, int k, int lb) {
  int c = lb * 256 + threadIdx.x;
  if (c >= NC1) return;
  int b = c / 100, ni = c - b * 100;
  int tBeg = k * S1;
  int tEnd = (tBeg + S1 < CT1) ? (tBeg + S1) : CT1;
  int nsteps = tEnd - tBeg;
  float* SV = st; float* SM = st + NC1; float* SN = st + 2 * NC1;
  float* SH = st + 3 * NC1; float* SY = st + 4 * NC1;
  float V, m, n, h, y;
  if (k == 0) {
    V = -70.f; m = 0.f; n = 0.f; h = 1.f; y = 0.f;
    T1s[c] = __expf((25.0f + 70.0f) * (1.0f / 9.0f));   // u for V0=-70
  } else { V = SV[c]; m = SM[c]; n = SN[c]; h = SH[c]; y = SY[c]; }
  const float* zp = z1s + ((size_t)b * CT1 + tBeg) * 100 + ni;
  float* tp = T1s + (size_t)(tBeg + 1) * NC1 + c;
  float zc[8], zx[8], ay[8], by[8], ry[8];
#pragma unroll
  for (int j = 0; j < 8; ++j) zc[j] = zp[j * 100];
  zp += 800;
  int NW = nsteps >> 3, tail = nsteps & 7;
  for (int i = 0; i < NW; ++i) {
#pragma unroll
    for (int j = 0; j < 8; ++j) zx[j] = zp[j * 100];   // z1s padded: unconditional
    zp += 800;
#pragma unroll
    for (int j = 0; j < 8; ++j) {                      // y-gate coefs off the chain
      float s = 0.005f * zc[j] + 0.0005f;
      ay[j] = zc[j] * 0.01f; by[j] = 1.0f - s; ry[j] = rcp_f(1.0f + s);
    }
#pragma unroll
    for (int j = 0; j < 8; ++j) {
      float u = hh_step(V, m, n, h, y, ay[j], by[j], ry[j]);
      *tp = u;                                         // raw u; sig in z2
      tp += NC1;
    }
#pragma unroll
    for (int j = 0; j < 8; ++j) zc[j] = zx[j];
  }
  for (int j = 0; j < tail; ++j) {
    float s = 0.005f * zc[j] + 0.0005f;
    float u = hh_step(V, m, n, h, y, zc[j] * 0.01f, 1.0f - s, rcp_f(1.0f + s));
    *tp = u;
    tp += NC1;
  }
  SV[c] = V; SM[c] = m; SN[c] = n; SH[c] = h; SY[c] = y;
}

// ---------- z2 chunk: applies sig_from_u to T1 (off the l1 chain) ----------
__device__ void z2_body(const float* __restrict__ T1s, const float* __restrict__ W2,
                        float* __restrict__ z2s, int k, int zb, char* smem) {
  float* w2 = (float*)smem;
  const int tid = threadIdx.x;
  if (tid < 250) *(float4*)&w2[tid * 4] = *(const float4*)&W2[tid * 4];
  __syncthreads();
  int tBeg = k * S1;
  int tEnd = (tBeg + S1 < CT2) ? (tBeg + S1) : CT2;
  int r = tBeg * NB + zb * 256 + tid;
  if (r >= tEnd * NB) return;
  const float* in = T1s + (size_t)r * 100;
  float acc[10];
#pragma unroll
  for (int o = 0; o < 10; ++o) acc[o] = 0.f;
  for (int k4 = 0; k4 < 25; ++k4) {
    float4 v = *(const float4*)(in + k4 * 4);
    v.x = sig_from_u(v.x); v.y = sig_from_u(v.y);
    v.z = sig_from_u(v.z); v.w = sig_from_u(v.w);
#pragma unroll
    for (int o = 0; o < 10; ++o) {
      float4 w = *(const float4*)&w2[o * 100 + k4 * 4];
      acc[o] += v.x * w.x + v.y * w.y + v.z * w.z + v.w * w.w;
    }
  }
  float* op = z2s + (size_t)r * 10;
#pragma unroll
  for (int o = 0; o < 10; o += 2) *(float2*)(op + o) = make_float2(acc[o], acc[o + 1]);
}

// ---------- L2 scan chunk (sigmoid inline; writes final out) ----------
__device__ void l2_body(const float* __restrict__ z2s, float* __restrict__ out,
                        float* __restrict__ st, int k, int lb) {
  int c2 = lb * 256 + threadIdx.x;
  if (c2 >= NC2) return;
  int b = c2 / 10, o = c2 - b * 10;
  int tBeg = k * S1;
  int tEnd = (tBeg + S1 < CT2) ? (tBeg + S1) : CT2;
  int nsteps = tEnd - tBeg;
  float* SV = st; float* SM = st + NC2; float* SN = st + 2 * NC2;
  float* SH = st + 3 * NC2; float* SY = st + 4 * NC2;
  float V, m, n, h, y;
  if (k == 0) {
    V = -70.f; m = 0.f; n = 0.f; h = 1.f; y = 1.f;
    out[(size_t)b * TT * 10 + o] = sigmoid3(-70.f);
  } else { V = SV[c2]; m = SM[c2]; n = SN[c2]; h = SH[c2]; y = SY[c2]; }
  const float* zp = z2s + (size_t)tBeg * NC2 + c2;
  float* op = out + ((size_t)b * TT + tBeg + 1) * 10 + o;
  float zc[8], zx[8], ay[8], by[8], ry[8];
#pragma unroll
  for (int j = 0; j < 8; ++j) zc[j] = zp[j * NC2];
  zp += 8 * NC2;
  int NW = nsteps >> 3, tail = nsteps & 7;
  for (int i = 0; i < NW; ++i) {
#pragma unroll
    for (int j = 0; j < 8; ++j) zx[j] = zp[j * NC2];   // z2s padded: unconditional
    zp += 8 * NC2;
#pragma unroll
    for (int j = 0; j < 8; ++j) {
      float s = 0.005f * zc[j] + 0.0005f;
      ay[j] = zc[j] * 0.01f; by[j] = 1.0f - s; ry[j] = rcp_f(1.0f + s);
    }
#pragma unroll
    for (int j = 0; j < 8; ++j) {
      float u = hh_step(V, m, n, h, y, ay[j], by[j], ry[j]);
      *op = sig_from_u(u);
      op += 10;
    }
#pragma unroll
    for (int j = 0; j < 8; ++j) zc[j] = zx[j];
  }
  for (int j = 0; j < tail; ++j) {
    float s = 0.005f * zc[j] + 0.0005f;
    float u = hh_step(V, m, n, h, y, zc[j] * 0.01f, 1.0f - s, rcp_f(1.0f + s));
    *op = sig_from_u(u);
    op += 10;
  }
  SV[c2] = V; SM[c2] = m; SN[c2] = n; SH[c2] = h; SY[c2] = y;
}

// ---------- scan pipeline dispatch: l1(d) | l2(d-2) | z2(d-1) only ----------
__global__ __launch_bounds__(256) void scan_pipe(
    const float* __restrict__ W2,
    const float* __restrict__ z1s, float* __restrict__ T1s, float* __restrict__ z2s,
    float* __restrict__ out, float* __restrict__ stL1, float* __restrict__ stL2,
    int kL1, int kZ2, int kL2, int nL1, int nL2, int nZ2) {
  __shared__ __align__(16) char smem[4096];
  int bid = (int)blockIdx.x;
  if (bid < nL1) { l1_body(z1s, T1s, stL1, kL1, bid); return; }
  bid -= nL1;
  if (bid < nL2) { l2_body(z2s, out, stL2, kL2, bid); return; }
  bid -= nL2;
  if (bid < nZ2) { z2_body(T1s, W2, z2s, kZ2, bid, smem); }
}

extern "C" void kernel_launch(void* const* d_in, const int* in_sizes, int n_in,
                              void* d_out, int out_size, void* d_ws, size_t ws_size,
                              hipStream_t stream) {
  (void)in_sizes; (void)n_in; (void)out_size; (void)ws_size;
  const float* batch = (const float*)d_in[0];
  const float* W1 = (const float*)d_in[1];
  const float* W2 = (const float*)d_in[2];
  float* out = (float*)d_out;

  float* z1s = (float*)d_ws;                                   // NB*CT1 x 100 (+16-row pad)
  float* T1s = z1s + (size_t)NB * CT1 * 100 + 1600;            // CT2 x NC1
  float* z2s = T1s + (size_t)CT2 * NC1;                        // CT2 x NC2 (+16-row pad)
  short* W1h = (short*)(z2s + (size_t)CT2 * NC2 + 16000);
  short* W1l = W1h + (size_t)NPAD * KPAD;
  float* stL1 = (float*)(W1l + (size_t)NPAD * KPAD);           // 5 x NC1
  float* stL2 = stL1 + 5 * NC1;                                // 5 x NC2

  prep_w1<<<dim3((NPAD * KPAD + 255) / 256), dim3(256), 0, stream>>>(W1, W1h, W1l);

  // Phase 1: whole GEMM, full machine (1600 blocks, 4-5/CU)
  gemm_all<<<dim3(NB * NCHUNK), dim3(256), 0, stream>>>(batch, W1h, W1l, z1s);

  // Phase 2: scan pipeline, 18 rounds of l1(d) | z2(d-1) | l2(d-2)
  for (int d = 0; d <= NCHUNK + 1; ++d) {
    int kL1 = d, kZ2 = d - 1, kL2 = d - 2;
    int nL1 = (kL1 >= 0 && kL1 < NCHUNK) ? (NC1 + 255) / 256 : 0;       // 40
    int nZ2 = 0;
    if (kZ2 >= 0 && kZ2 < NCHUNK) {
      int tBeg = kZ2 * S1;
      int tEnd = (tBeg + S1 < CT2) ? (tBeg + S1) : CT2;
      nZ2 = ((tEnd - tBeg) * NB + 255) / 256;                           // <= 50
    }
    int nL2 = (kL2 >= 0 && kL2 < NCHUNK) ? (NC2 + 255) / 256 : 0;       // 4
    int grid = nL1 + nL2 + nZ2;
    if (grid == 0) continue;
    scan_pipe<<<dim3((unsigned)grid), dim3(256), 0, stream>>>(
        W2, z1s, T1s, z2s, out, stL1, stL2, kL1, kZ2, kL2, nL1, nL2, nZ2);
  }
}